// Round 1
// baseline (227.727 us; speedup 1.0000x reference)
//
#include <hip/hip_runtime.h>

#define PI_D 3.14159265358979323846

// ws float layout
#define OFF_TW 0
#define OFF_WT 256
#define OFF_XF (256 + 1048576)
#define OFF_YF (256 + 2*1048576)
// total floats: 256 + 3*1048576 = 3,145,984  (~12.6 MB)

// ---------------- twiddle table: tw[j] = (cos(2pi j/128), sin(2pi j/128)) -------------
__global__ void k_prep_tw(float* ws) {
    int j = threadIdx.x;  // 0..127
    double a = (2.0 * PI_D / 128.0) * j;
    float2* tw = (float2*)(ws + OFF_TW);
    tw[j] = make_float2((float)cos(a), (float)sin(a));
}

// ---------------- weight transpose: w[i][o][m][ky] -> wt[(m*16+ky)][i*32+o] (complex) --
__global__ __launch_bounds__(256) void k_prep_wt(const float* __restrict__ wr,
                                                 const float* __restrict__ wi,
                                                 float* ws) {
    __shared__ float lsr[32 * 16];
    __shared__ float lsi[32 * 16];
    int bid = blockIdx.x;            // i*32 + m
    int i = bid >> 5, m = bid & 31;
    int t = threadIdx.x;
    for (int it = 0; it < 2; ++it) {
        int idx = t + 256 * it;      // 0..511
        int o = idx >> 4, ky = idx & 15;
        int g = ((i * 32 + o) * 32 + m) * 16 + ky;
        lsr[o * 16 + ky] = wr[g];
        lsi[o * 16 + ky] = wi[g];
    }
    __syncthreads();
    float2* wt = (float2*)(ws + OFF_WT);
    for (int it = 0; it < 2; ++it) {
        int idx = t + 256 * it;
        int ky = idx >> 5, o = idx & 31;
        wt[(size_t)(m * 16 + ky) * 1024 + i * 32 + o] =
            make_float2(lsr[o * 16 + ky], lsi[o * 16 + ky]);
    }
}

// ---------------- forward truncated DFT: x[b,i,:,:] -> xf[mode][b*32+i] ----------------
__global__ __launch_bounds__(256) void k_fwd(const float* __restrict__ x, float* ws) {
    __shared__ float xs[128][33];    // [row][0..15: w-chunk, 16..31: w+64 chunk]
    __shared__ float2 Y[128][17];    // padded
    __shared__ float2 ltw[128];
    int t = threadIdx.x;
    int bid = blockIdx.x;            // b*32 + i
    const float2* tw = (const float2*)(ws + OFF_TW);
    if (t < 128) ltw[t] = tw[t];
    __syncthreads();

    // ---- phase 1: Y[x][ky] = sum_w x[x][w] e^{-2pi i w ky/128}, ky=0..15
    // pair w, w+64:  Y[ky] = sum_{w<64} (x[w] + (-1)^ky x[w+64]) * e^{-2pi i w ky/128}
    int xr = t >> 1, kg = t & 1;
    int kyb = kg * 8;
    float pr[8], pi[8], rr[8], ri[8], aR[8], aI[8];
#pragma unroll
    for (int j = 0; j < 8; j++) {
        float2 w1 = ltw[kyb + j];
        rr[j] = w1.x; ri[j] = -w1.y;   // e^{-2pi i ky/128}
        pr[j] = 1.f; pi[j] = 0.f;
        aR[j] = 0.f; aI[j] = 0.f;
    }
    const float* xim = x + (size_t)bid * 128 * 128;
    for (int c = 0; c < 4; c++) {
        __syncthreads();
        for (int it = 0; it < 4; ++it) {
            int u = t + 256 * it;            // 0..1023
            int row = u >> 3, q = u & 7;
            int col = (q < 4) ? (16 * c + 4 * q) : (64 + 16 * c + 4 * (q - 4));
            const float4 v = *(const float4*)(xim + row * 128 + col);
            int lc = (q < 4) ? 4 * q : 16 + 4 * (q - 4);
            xs[row][lc + 0] = v.x; xs[row][lc + 1] = v.y;
            xs[row][lc + 2] = v.z; xs[row][lc + 3] = v.w;
        }
        __syncthreads();
        for (int wl = 0; wl < 16; ++wl) {
            float x0 = xs[xr][wl], x1 = xs[xr][16 + wl];
            float ue = x0 + x1, uo = x0 - x1;
#pragma unroll
            for (int j = 0; j < 8; j++) {
                float u = ((kyb + j) & 1) ? uo : ue;
                aR[j] = fmaf(u, pr[j], aR[j]);
                aI[j] = fmaf(u, pi[j], aI[j]);
                float npr = pr[j] * rr[j] - pi[j] * ri[j];
                float npi = pr[j] * ri[j] + pi[j] * rr[j];
                pr[j] = npr; pi[j] = npi;
            }
        }
    }
#pragma unroll
    for (int j = 0; j < 8; j++) Y[xr][kyb + j] = make_float2(aR[j], aI[j]);
    __syncthreads();

    // ---- phase 2: Xf[m][ky] = (1/128) sum_x Y[x][ky] e^{-2pi i x kx/128}
    // thread t handles modes t (m=t>>4, kx=m) and t+256 (m+16, kx=112+m); same ky.
    int m = t >> 4, ky = t & 15;
    float2 w1 = ltw[m];
    float2 w2 = ltw[(112 + m) & 127];
    float r1r = w1.x, r1i = -w1.y;
    float r2r = w2.x, r2i = -w2.y;
    float p1r = 1.f, p1i = 0.f, p2r = 1.f, p2i = 0.f;
    float a1r = 0, a1i = 0, a2r = 0, a2i = 0;
    for (int xx = 0; xx < 128; ++xx) {
        float2 yv = Y[xx][ky];
        a1r = fmaf(yv.x, p1r, fmaf(-yv.y, p1i, a1r));
        a1i = fmaf(yv.x, p1i, fmaf( yv.y, p1r, a1i));
        a2r = fmaf(yv.x, p2r, fmaf(-yv.y, p2i, a2r));
        a2i = fmaf(yv.x, p2i, fmaf( yv.y, p2r, a2i));
        float n1r = p1r * r1r - p1i * r1i, n1i = p1r * r1i + p1i * r1r;
        float n2r = p2r * r2r - p2i * r2i, n2i = p2r * r2i + p2i * r2r;
        p1r = n1r; p1i = n1i; p2r = n2r; p2i = n2i;
    }
    float2* xf = (float2*)(ws + OFF_XF);
    float s = 1.f / 128.f;
    xf[(size_t)t * 1024 + bid]         = make_float2(a1r * s, a1i * s);
    xf[(size_t)(t + 256) * 1024 + bid] = make_float2(a2r * s, a2i * s);
}

// ---------------- channel mix: yf[mode][b][o] = sum_i xf[mode][b][i] * wt[mode][i][o] --
__global__ __launch_bounds__(256) void k_mix(float* ws) {
    __shared__ float2 xsh[1024];
    __shared__ float2 wsh[1024];
    int t = threadIdx.x;
    int mode = blockIdx.x;
    const float4* xg = (const float4*)((const float2*)(ws + OFF_XF) + (size_t)mode * 1024);
    const float4* wg = (const float4*)((const float2*)(ws + OFF_WT) + (size_t)mode * 1024);
    float4* xs4 = (float4*)xsh; float4* ws4 = (float4*)wsh;
    xs4[t] = xg[t]; xs4[t + 256] = xg[t + 256];
    ws4[t] = wg[t]; ws4[t + 256] = wg[t + 256];
    __syncthreads();
    int o = t & 31, b0 = t >> 5;
    float ar[4] = {0, 0, 0, 0}, ai[4] = {0, 0, 0, 0};
    for (int i = 0; i < 32; ++i) {
        float2 wv = wsh[i * 32 + o];
#pragma unroll
        for (int bb = 0; bb < 4; ++bb) {
            float2 xv = xsh[(b0 + 8 * bb) * 32 + i];
            ar[bb] = fmaf(xv.x, wv.x, fmaf(-xv.y, wv.y, ar[bb]));
            ai[bb] = fmaf(xv.x, wv.y, fmaf( xv.y, wv.x, ai[bb]));
        }
    }
    float2* yf = (float2*)(ws + OFF_YF) + (size_t)mode * 1024;
#pragma unroll
    for (int bb = 0; bb < 4; ++bb)
        yf[(b0 + 8 * bb) * 32 + o] = make_float2(ar[bb], ai[bb]);
}

// ---------------- inverse: yf[.][b*32+o] -> out[b,o,:,:] ------------------------------
__global__ __launch_bounds__(256) void k_inv(const float* __restrict__ ws_c, float* __restrict__ out) {
    const float* ws = ws_c;
    __shared__ float2 zm[512];
    __shared__ float2 Z[128][17];
    __shared__ float2 ltw[128];
    int t = threadIdx.x;
    int bid = blockIdx.x;                 // b*32 + o
    const float2* tw = (const float2*)(ws + OFF_TW);
    if (t < 128) ltw[t] = tw[t];
    const float2* yf = (const float2*)(ws + OFF_YF);
    zm[t]       = yf[(size_t)t * 1024 + bid];
    zm[t + 256] = yf[(size_t)(t + 256) * 1024 + bid];
    __syncthreads();

    // ---- phase 1: Z[x][ky] = sum_m zm[m*16+ky] * e^{+2pi i x kx(m)/128}
    // m<16: kx=m (phasor from 1, rotate e^{+2pi i x/128});
    // m>=16: kx=96+m=112..127, start = e^{+2pi i 112x/128} = conj(e^{+2pi i 16x/128})
    int ky = t & 15, xg = t >> 4;         // xg 0..15
    for (int c = 0; c < 8; ++c) {
        int xx = xg + 16 * c;
        float2 rw = ltw[xx];
        float rr_ = rw.x, ri_ = rw.y;
        float p_r = 1.f, p_i = 0.f, zr = 0.f, zi = 0.f;
#pragma unroll
        for (int m = 0; m < 16; ++m) {
            float2 zv = zm[m * 16 + ky];
            zr = fmaf(zv.x, p_r, fmaf(-zv.y, p_i, zr));
            zi = fmaf(zv.x, p_i, fmaf( zv.y, p_r, zi));
            float nr = p_r * rr_ - p_i * ri_, ni = p_r * ri_ + p_i * rr_;
            p_r = nr; p_i = ni;
        }
        p_i = -p_i;                        // conj -> e^{+2pi i 112x/128}
#pragma unroll
        for (int m = 16; m < 32; ++m) {
            float2 zv = zm[m * 16 + ky];
            zr = fmaf(zv.x, p_r, fmaf(-zv.y, p_i, zr));
            zi = fmaf(zv.x, p_i, fmaf( zv.y, p_r, zi));
            float nr = p_r * rr_ - p_i * ri_, ni = p_r * ri_ + p_i * rr_;
            p_r = nr; p_i = ni;
        }
        Z[xx][ky] = make_float2(zr, zi);
    }
    __syncthreads();

    // ---- phase 2: out[x][y] = sum_{k=0..15} (c_k/128) Re( Z[x][k] e^{+2pi i y k/128} )
    // thread: x = t>>1, h = t&1 covers y in [32h,32h+32) and +64 (sign trick).
    int xr = t >> 1, h = t & 1;
    float qr[16], qi[16], rr2[16], ri2[16];
#pragma unroll
    for (int k = 0; k < 16; ++k) {
        float2 a = Z[xr][k];
        float sc = (k == 0) ? (1.f / 128.f) : (1.f / 64.f);
        float are = a.x * sc, aim = a.y * sc;
        if (h) {                            // multiply by i^k  (y0 = 32)
            int ph = k & 3;
            if (ph == 0)      { qr[k] =  are; qi[k] =  aim; }
            else if (ph == 1) { qr[k] = -aim; qi[k] =  are; }
            else if (ph == 2) { qr[k] = -are; qi[k] = -aim; }
            else              { qr[k] =  aim; qi[k] = -are; }
        } else { qr[k] = are; qi[k] = aim; }
        float2 w1 = ltw[k];
        rr2[k] = w1.x; ri2[k] = w1.y;      // e^{+2pi i k/128}
    }
    float* orow = out + (size_t)bid * 16384 + xr * 128 + 32 * h;
    float buf_lo[4], buf_hi[4];
    for (int j = 0; j < 32; ++j) {
        float se = qr[0] + qr[2] + qr[4] + qr[6] + qr[8] + qr[10] + qr[12] + qr[14];
        float so = qr[1] + qr[3] + qr[5] + qr[7] + qr[9] + qr[11] + qr[13] + qr[15];
        buf_lo[j & 3] = se + so;           // y
        buf_hi[j & 3] = se - so;           // y + 64
#pragma unroll
        for (int k = 1; k < 16; ++k) {
            float nr = qr[k] * rr2[k] - qi[k] * ri2[k];
            float ni = qr[k] * ri2[k] + qi[k] * rr2[k];
            qr[k] = nr; qi[k] = ni;
        }
        if ((j & 3) == 3) {
            *(float4*)(orow + (j - 3))      = make_float4(buf_lo[0], buf_lo[1], buf_lo[2], buf_lo[3]);
            *(float4*)(orow + 64 + (j - 3)) = make_float4(buf_hi[0], buf_hi[1], buf_hi[2], buf_hi[3]);
        }
    }
}

extern "C" void kernel_launch(void* const* d_in, const int* in_sizes, int n_in,
                              void* d_out, int out_size, void* d_ws, size_t ws_size,
                              hipStream_t stream) {
    const float* x  = (const float*)d_in[0];
    const float* wr = (const float*)d_in[1];
    const float* wi = (const float*)d_in[2];
    float* out = (float*)d_out;
    float* ws  = (float*)d_ws;
    k_prep_tw<<<dim3(1),    dim3(128), 0, stream>>>(ws);
    k_prep_wt<<<dim3(1024), dim3(256), 0, stream>>>(wr, wi, ws);
    k_fwd    <<<dim3(1024), dim3(256), 0, stream>>>(x, ws);
    k_mix    <<<dim3(512),  dim3(256), 0, stream>>>(ws);
    k_inv    <<<dim3(1024), dim3(256), 0, stream>>>(ws, out);
}

// Round 2
// 197.029 us; speedup vs baseline: 1.1558x; 1.1558x over previous
//
#include <hip/hip_runtime.h>

#define PI_D 3.14159265358979323846

// ws float layout
#define OFF_TW 0
#define OFF_WT 256
#define OFF_XF (256 + 1048576)
#define OFF_YF (256 + 2*1048576)
// total floats: 256 + 3*1048576 = 3,145,984  (~12.6 MB)

// ---------------- twiddle table: tw[j] = (cos(2pi j/128), sin(2pi j/128)) -------------
__global__ void k_prep_tw(float* ws) {
    int j = threadIdx.x;  // 0..127
    double a = (2.0 * PI_D / 128.0) * j;
    float2* tw = (float2*)(ws + OFF_TW);
    tw[j] = make_float2((float)cos(a), (float)sin(a));
}

// ---------------- weight transpose: w[i][o][m][ky] -> wt[(m*16+ky)][i*32+o] (complex) --
__global__ __launch_bounds__(256) void k_prep_wt(const float* __restrict__ wr,
                                                 const float* __restrict__ wi,
                                                 float* ws) {
    __shared__ float lsr[32 * 16];
    __shared__ float lsi[32 * 16];
    int bid = blockIdx.x;            // i*32 + m
    int i = bid >> 5, m = bid & 31;
    int t = threadIdx.x;
    for (int it = 0; it < 2; ++it) {
        int idx = t + 256 * it;      // 0..511
        int o = idx >> 4, ky = idx & 15;
        int g = ((i * 32 + o) * 32 + m) * 16 + ky;
        lsr[o * 16 + ky] = wr[g];
        lsi[o * 16 + ky] = wi[g];
    }
    __syncthreads();
    float2* wt = (float2*)(ws + OFF_WT);
    for (int it = 0; it < 2; ++it) {
        int idx = t + 256 * it;
        int ky = idx >> 5, o = idx & 31;
        wt[(size_t)(m * 16 + ky) * 1024 + i * 32 + o] =
            make_float2(lsr[o * 16 + ky], lsi[o * 16 + ky]);
    }
}

// ---------------- forward truncated DFT: x[b,i,:,:] -> xf[bid][mode] (bid-major!) ------
__global__ __launch_bounds__(256) void k_fwd(const float* __restrict__ x, float* ws) {
    __shared__ float xs[128][33];    // [row][0..15: w-chunk, 16..31: w+64 chunk]
    __shared__ float2 Y[128][17];    // padded
    __shared__ float2 ltw[128];
    int t = threadIdx.x;
    int bid = blockIdx.x;            // b*32 + i
    const float2* tw = (const float2*)(ws + OFF_TW);
    if (t < 128) ltw[t] = tw[t];
    __syncthreads();

    // ---- phase 1: Y[x][ky] = sum_w x[x][w] e^{-2pi i w ky/128}, ky=0..15
    // pair w, w+64:  Y[ky] = sum_{w<64} (x[w] + (-1)^ky x[w+64]) * e^{-2pi i w ky/128}
    int xr = t >> 1, kg = t & 1;
    int kyb = kg * 8;
    float pr[8], pi[8], rr[8], ri[8], aR[8], aI[8];
#pragma unroll
    for (int j = 0; j < 8; j++) {
        float2 w1 = ltw[kyb + j];
        rr[j] = w1.x; ri[j] = -w1.y;   // e^{-2pi i ky/128}
        pr[j] = 1.f; pi[j] = 0.f;
        aR[j] = 0.f; aI[j] = 0.f;
    }
    const float* xim = x + (size_t)bid * 128 * 128;
    for (int c = 0; c < 4; c++) {
        __syncthreads();
        for (int it = 0; it < 4; ++it) {
            int u = t + 256 * it;            // 0..1023
            int row = u >> 3, q = u & 7;
            int col = (q < 4) ? (16 * c + 4 * q) : (64 + 16 * c + 4 * (q - 4));
            const float4 v = *(const float4*)(xim + row * 128 + col);
            int lc = (q < 4) ? 4 * q : 16 + 4 * (q - 4);
            xs[row][lc + 0] = v.x; xs[row][lc + 1] = v.y;
            xs[row][lc + 2] = v.z; xs[row][lc + 3] = v.w;
        }
        __syncthreads();
        for (int wl = 0; wl < 16; ++wl) {
            float x0 = xs[xr][wl], x1 = xs[xr][16 + wl];
            float ue = x0 + x1, uo = x0 - x1;
#pragma unroll
            for (int j = 0; j < 8; j++) {
                float u = ((kyb + j) & 1) ? uo : ue;
                aR[j] = fmaf(u, pr[j], aR[j]);
                aI[j] = fmaf(u, pi[j], aI[j]);
                float npr = pr[j] * rr[j] - pi[j] * ri[j];
                float npi = pr[j] * ri[j] + pi[j] * rr[j];
                pr[j] = npr; pi[j] = npi;
            }
        }
    }
#pragma unroll
    for (int j = 0; j < 8; j++) Y[xr][kyb + j] = make_float2(aR[j], aI[j]);
    __syncthreads();

    // ---- phase 2: Xf[m][ky] = (1/128) sum_x Y[x][ky] e^{-2pi i x kx/128}
    // thread t handles modes t (m=t>>4, kx=m) and t+256 (m+16, kx=112+m); same ky.
    int m = t >> 4, ky = t & 15;
    float2 w1 = ltw[m];
    float2 w2 = ltw[(112 + m) & 127];
    float r1r = w1.x, r1i = -w1.y;
    float r2r = w2.x, r2i = -w2.y;
    float p1r = 1.f, p1i = 0.f, p2r = 1.f, p2i = 0.f;
    float a1r = 0, a1i = 0, a2r = 0, a2i = 0;
    for (int xx = 0; xx < 128; ++xx) {
        float2 yv = Y[xx][ky];
        a1r = fmaf(yv.x, p1r, fmaf(-yv.y, p1i, a1r));
        a1i = fmaf(yv.x, p1i, fmaf( yv.y, p1r, a1i));
        a2r = fmaf(yv.x, p2r, fmaf(-yv.y, p2i, a2r));
        a2i = fmaf(yv.x, p2i, fmaf( yv.y, p2r, a2i));
        float n1r = p1r * r1r - p1i * r1i, n1i = p1r * r1i + p1i * r1r;
        float n2r = p2r * r2r - p2i * r2i, n2i = p2r * r2i + p2i * r2r;
        p1r = n1r; p1i = n1i; p2r = n2r; p2i = n2i;
    }
    // bid-major layout: wave writes 64 contiguous float2 = 512 B (coalesced)
    float2* xf = (float2*)(ws + OFF_XF);
    float s = 1.f / 128.f;
    xf[(size_t)bid * 512 + t]       = make_float2(a1r * s, a1i * s);
    xf[(size_t)bid * 512 + t + 256] = make_float2(a2r * s, a2i * s);
}

// ---------------- channel mix: yf[mode][b][o] = sum_i xf[bid][mode] * wt[mode][i][o] --
__global__ __launch_bounds__(256) void k_mix(float* ws) {
    __shared__ float2 xsh[1024];
    __shared__ float2 wsh[1024];
    int t = threadIdx.x;
    int mode = blockIdx.x;
    const float2* xf = (const float2*)(ws + OFF_XF);
    // gather: xsh[bid] = xf[bid][mode]  (8B reads, 4KB stride; LLC-absorbed)
#pragma unroll
    for (int r = 0; r < 4; ++r)
        xsh[t + 256 * r] = xf[(size_t)(t + 256 * r) * 512 + mode];
    const float4* wg = (const float4*)((const float2*)(ws + OFF_WT) + (size_t)mode * 1024);
    float4* ws4 = (float4*)wsh;
    ws4[t] = wg[t]; ws4[t + 256] = wg[t + 256];
    __syncthreads();
    int o = t & 31, b0 = t >> 5;
    float ar[4] = {0, 0, 0, 0}, ai[4] = {0, 0, 0, 0};
    for (int i = 0; i < 32; ++i) {
        float2 wv = wsh[i * 32 + o];
#pragma unroll
        for (int bb = 0; bb < 4; ++bb) {
            float2 xv = xsh[(b0 + 8 * bb) * 32 + i];
            ar[bb] = fmaf(xv.x, wv.x, fmaf(-xv.y, wv.y, ar[bb]));
            ai[bb] = fmaf(xv.x, wv.y, fmaf( xv.y, wv.x, ai[bb]));
        }
    }
    float2* yf = (float2*)(ws + OFF_YF) + (size_t)mode * 1024;
#pragma unroll
    for (int bb = 0; bb < 4; ++bb)
        yf[(b0 + 8 * bb) * 32 + o] = make_float2(ar[bb], ai[bb]);
}

// ---------------- inverse: yf[.][b*32+o] -> out[b,o,:,:] ------------------------------
__global__ __launch_bounds__(256) void k_inv(const float* __restrict__ ws_c, float* __restrict__ out) {
    const float* ws = ws_c;
    __shared__ float2 zm[512];
    __shared__ float2 Z[128][17];
    __shared__ float2 ltw[128];
    int t = threadIdx.x;
    int bid = blockIdx.x;                 // b*32 + o
    const float2* tw = (const float2*)(ws + OFF_TW);
    if (t < 128) ltw[t] = tw[t];
    const float2* yf = (const float2*)(ws + OFF_YF);
    zm[t]       = yf[(size_t)t * 1024 + bid];
    zm[t + 256] = yf[(size_t)(t + 256) * 1024 + bid];
    __syncthreads();

    // ---- phase 1: Z[x][ky] = sum_m zm[m*16+ky] * e^{+2pi i x kx(m)/128}
    int ky = t & 15, xg = t >> 4;         // xg 0..15
    for (int c = 0; c < 8; ++c) {
        int xx = xg + 16 * c;
        float2 rw = ltw[xx];
        float rr_ = rw.x, ri_ = rw.y;
        float p_r = 1.f, p_i = 0.f, zr = 0.f, zi = 0.f;
#pragma unroll
        for (int m = 0; m < 16; ++m) {
            float2 zv = zm[m * 16 + ky];
            zr = fmaf(zv.x, p_r, fmaf(-zv.y, p_i, zr));
            zi = fmaf(zv.x, p_i, fmaf( zv.y, p_r, zi));
            float nr = p_r * rr_ - p_i * ri_, ni = p_r * ri_ + p_i * rr_;
            p_r = nr; p_i = ni;
        }
        p_i = -p_i;                        // conj -> e^{+2pi i 112x/128}
#pragma unroll
        for (int m = 16; m < 32; ++m) {
            float2 zv = zm[m * 16 + ky];
            zr = fmaf(zv.x, p_r, fmaf(-zv.y, p_i, zr));
            zi = fmaf(zv.x, p_i, fmaf( zv.y, p_r, zi));
            float nr = p_r * rr_ - p_i * ri_, ni = p_r * ri_ + p_i * rr_;
            p_r = nr; p_i = ni;
        }
        Z[xx][ky] = make_float2(zr, zi);
    }
    __syncthreads();

    // ---- phase 2: out[x][y] = sum_{k=0..15} (c_k/128) Re( Z[x][k] e^{+2pi i y k/128} )
    // thread: x = t>>1, h = t&1 covers y in [32h,32h+32) and +64 (sign trick).
    // Buffer 16 lo + 16 hi in regs, then burst-store each complete 64B line as
    // 4 back-to-back float4 stores so L2 merges full lines (no partial-line evicts).
    int xr = t >> 1, h = t & 1;
    float qr[16], qi[16], rr2[16], ri2[16];
#pragma unroll
    for (int k = 0; k < 16; ++k) {
        float2 a = Z[xr][k];
        float sc = (k == 0) ? (1.f / 128.f) : (1.f / 64.f);
        float are = a.x * sc, aim = a.y * sc;
        if (h) {                            // multiply by i^k  (y0 = 32)
            int ph = k & 3;
            if (ph == 0)      { qr[k] =  are; qi[k] =  aim; }
            else if (ph == 1) { qr[k] = -aim; qi[k] =  are; }
            else if (ph == 2) { qr[k] = -are; qi[k] = -aim; }
            else              { qr[k] =  aim; qi[k] = -are; }
        } else { qr[k] = are; qi[k] = aim; }
        float2 w1 = ltw[k];
        rr2[k] = w1.x; ri2[k] = w1.y;      // e^{+2pi i k/128}
    }
    float* orow = out + (size_t)bid * 16384 + xr * 128 + 32 * h;
    float lo[16], hi[16];
#pragma unroll
    for (int half = 0; half < 2; ++half) {
#pragma unroll
        for (int j = 0; j < 16; ++j) {
            float se = qr[0] + qr[2] + qr[4] + qr[6] + qr[8] + qr[10] + qr[12] + qr[14];
            float so = qr[1] + qr[3] + qr[5] + qr[7] + qr[9] + qr[11] + qr[13] + qr[15];
            lo[j] = se + so;               // y
            hi[j] = se - so;               // y + 64
#pragma unroll
            for (int k = 1; k < 16; ++k) {
                float nr = qr[k] * rr2[k] - qi[k] * ri2[k];
                float ni = qr[k] * ri2[k] + qi[k] * rr2[k];
                qr[k] = nr; qi[k] = ni;
            }
        }
        float4* p0 = (float4*)(orow + 16 * half);
        p0[0] = make_float4(lo[0],  lo[1],  lo[2],  lo[3]);
        p0[1] = make_float4(lo[4],  lo[5],  lo[6],  lo[7]);
        p0[2] = make_float4(lo[8],  lo[9],  lo[10], lo[11]);
        p0[3] = make_float4(lo[12], lo[13], lo[14], lo[15]);
        float4* p1 = (float4*)(orow + 64 + 16 * half);
        p1[0] = make_float4(hi[0],  hi[1],  hi[2],  hi[3]);
        p1[1] = make_float4(hi[4],  hi[5],  hi[6],  hi[7]);
        p1[2] = make_float4(hi[8],  hi[9],  hi[10], hi[11]);
        p1[3] = make_float4(hi[12], hi[13], hi[14], hi[15]);
    }
}

extern "C" void kernel_launch(void* const* d_in, const int* in_sizes, int n_in,
                              void* d_out, int out_size, void* d_ws, size_t ws_size,
                              hipStream_t stream) {
    const float* x  = (const float*)d_in[0];
    const float* wr = (const float*)d_in[1];
    const float* wi = (const float*)d_in[2];
    float* out = (float*)d_out;
    float* ws  = (float*)d_ws;
    k_prep_tw<<<dim3(1),    dim3(128), 0, stream>>>(ws);
    k_prep_wt<<<dim3(1024), dim3(256), 0, stream>>>(wr, wi, ws);
    k_fwd    <<<dim3(1024), dim3(256), 0, stream>>>(x, ws);
    k_mix    <<<dim3(512),  dim3(256), 0, stream>>>(ws);
    k_inv    <<<dim3(1024), dim3(256), 0, stream>>>(ws, out);
}

// Round 3
// 145.291 us; speedup vs baseline: 1.5674x; 1.3561x over previous
//
#include <hip/hip_runtime.h>

#define PI_D 3.14159265358979323846

typedef __attribute__((ext_vector_type(8))) short bf16x8;
typedef __attribute__((ext_vector_type(4))) float f32x4;

static __device__ inline f32x4 mfma16(bf16x8 a, bf16x8 b, f32x4 c) {
    return __builtin_amdgcn_mfma_f32_16x16x32_bf16(a, b, c, 0, 0, 0);
}

static __device__ inline unsigned short f2bf(float f) {
    union { float f; unsigned u; } v; v.f = f;
    unsigned u = v.u;
    u += 0x7fffu + ((u >> 16) & 1u);   // RNE
    return (unsigned short)(u >> 16);
}

// ---- ws float layout ----------------------------------------------------------------
#define OFF_TAB 0                         // 32768 bf16 = 16384 floats
#define OFF_WT   16384                    // 512 modes x 1024 x complex f32 = 1,048,576 fl
#define OFF_XFR  (16384 + 1048576)        // 1024 bids x 512 modes f32 (re)
#define OFF_XFI  (OFF_XFR + 524288)       // (im)
#define OFF_YF   (OFF_XFI + 524288)       // 512 modes x 1024 x complex f32
// total = 3,162,112 floats ~ 12.65 MB

// table offsets in u16 units within OFF_TAB
#define TAB_E1 0        // [32 n=c*16+ky][128 w]
#define TAB_A2 4096     // [64 row=p*32+m][256 k=c*128+x]
#define TAB_A3 20480    // [128 x][64 k=c*32+m]
#define TAB_E4 28672    // [128 y][32 k=p*16+ky]

// ---------------- table prep (bf16) ---------------------------------------------------
__global__ __launch_bounds__(256) void k_prep_e(float* ws) {
    int gid = blockIdx.x * 256 + threadIdx.x;   // 0..32767
    unsigned short* tab = (unsigned short*)(ws + OFF_TAB);
    const float W128 = (float)(2.0 * PI_D / 128.0);
    if (gid < 4096) {                       // E1t: forward y-DFT, x(1/128) scale
        int n = gid >> 7, w = gid & 127;
        int ky = n & 15, c = n >> 4;
        float th = ((w * ky) & 127) * W128;
        float val = (c ? -sinf(th) : cosf(th)) * (1.f / 128.f);
        tab[TAB_E1 + gid] = f2bf(val);
    } else if (gid < 20480) {               // A2: forward x-DFT (complex-as-real)
        int idx = gid - 4096;
        int row = idx >> 8, k = idx & 255;
        int p = row >> 5, m = row & 31;
        int c = k >> 7, xx = k & 127;
        int kx = (m < 16) ? m : 96 + m;
        float th = ((xx * kx) & 127) * W128;
        float er = cosf(th), ei = -sinf(th);
        float val = (p == 0) ? (c == 0 ? er : -ei) : (c == 0 ? ei : er);
        tab[TAB_A2 + idx] = f2bf(val);
    } else if (gid < 28672) {               // A3: inverse x-DFT
        int idx = gid - 20480;
        int xx = idx >> 6, k = idx & 63;
        int c = k >> 5, m = k & 31;
        int kx = (m < 16) ? m : 96 + m;
        float th = ((xx * kx) & 127) * W128;
        float er = cosf(th), ei = sinf(th);
        float val = (c == 0) ? er : -ei;
        tab[TAB_A3 + idx] = f2bf(val);
    } else {                                // E4t: inverse y-DFT w/ hermitian weights
        int idx = gid - 28672;
        int y = idx >> 5, k = idx & 31;
        int p = k >> 4, ky = k & 15;
        float th = ((y * ky) & 127) * W128;
        float sc = (ky == 0 ? 1.f : 2.f) / 128.f;
        float val = (p == 0) ? sc * cosf(th) : -sc * sinf(th);
        tab[TAB_E4 + idx] = f2bf(val);
    }
}

// ---------------- weight transpose: w[i][o][m][ky] -> wt[(m*16+ky)][i*32+o] (complex) --
__global__ __launch_bounds__(256) void k_prep_wt(const float* __restrict__ wr,
                                                 const float* __restrict__ wi,
                                                 float* ws) {
    __shared__ float lsr[32 * 16];
    __shared__ float lsi[32 * 16];
    int bid = blockIdx.x;            // i*32 + m
    int i = bid >> 5, m = bid & 31;
    int t = threadIdx.x;
    for (int it = 0; it < 2; ++it) {
        int idx = t + 256 * it;      // 0..511
        int o = idx >> 4, ky = idx & 15;
        int g = ((i * 32 + o) * 32 + m) * 16 + ky;
        lsr[o * 16 + ky] = wr[g];
        lsi[o * 16 + ky] = wi[g];
    }
    __syncthreads();
    float2* wt = (float2*)(ws + OFF_WT);
    for (int it = 0; it < 2; ++it) {
        int idx = t + 256 * it;
        int ky = idx >> 5, o = idx & 31;
        wt[(size_t)(m * 16 + ky) * 1024 + i * 32 + o] =
            make_float2(lsr[o * 16 + ky], lsi[o * 16 + ky]);
    }
}

// ---------------- forward: x[bid,:,:] --MFMA--> xfr/xfi[bid][mode] --------------------
__global__ __launch_bounds__(256) void k_f(const float* __restrict__ x, float* ws) {
    __shared__ __align__(16) unsigned short Xl[128 * 136];   // x image bf16, pad->16B rows
    __shared__ __align__(16) unsigned short E1l[32 * 136];   // E1t staged
    __shared__ __align__(16) unsigned short Yl[16 * 264];    // Y: [ky][k=c*128+x]
    int t = threadIdx.x, bid = blockIdx.x;
    const unsigned short* tab = (const unsigned short*)(ws + OFF_TAB);

    // stage E1t (32x128 -> stride 136)
    for (int c = t; c < 512; c += 256) {
        int row = c >> 4, seg = c & 15;
        *(uint4*)&E1l[row * 136 + seg * 8] = *(const uint4*)&tab[TAB_E1 + row * 128 + seg * 8];
    }
    // stage X (f32 -> bf16)
    const float* xim = x + (size_t)bid * 16384;
    for (int it = 0; it < 16; ++it) {
        int row = it * 8 + (t >> 5), c4 = (t & 31) * 4;
        float4 v = *(const float4*)(xim + row * 128 + c4);
        ushort4 h;
        h.x = f2bf(v.x); h.y = f2bf(v.y); h.z = f2bf(v.z); h.w = f2bf(v.w);
        *(ushort4*)&Xl[row * 136 + c4] = h;
    }
    __syncthreads();

    int lid = t & 15, q = (t >> 4) & 3, w = t >> 6;

    // F1: C[x][(c,ky)] = sum_w X[x][w] E1t[(c,ky)][w];  M=128 N=32 K=128
    f32x4 acc[2][2] = {};
#pragma unroll
    for (int ks = 0; ks < 4; ++ks) {
        bf16x8 a0 = *(const bf16x8*)&Xl[(32 * w + lid) * 136 + ks * 32 + q * 8];
        bf16x8 a1 = *(const bf16x8*)&Xl[(32 * w + 16 + lid) * 136 + ks * 32 + q * 8];
        bf16x8 b0 = *(const bf16x8*)&E1l[lid * 136 + ks * 32 + q * 8];
        bf16x8 b1 = *(const bf16x8*)&E1l[(16 + lid) * 136 + ks * 32 + q * 8];
        acc[0][0] = mfma16(a0, b0, acc[0][0]);
        acc[0][1] = mfma16(a0, b1, acc[0][1]);
        acc[1][0] = mfma16(a1, b0, acc[1][0]);
        acc[1][1] = mfma16(a1, b1, acc[1][1]);
    }
    // epilogue: Y -> Yl[ky][c*128+x] bf16
#pragma unroll
    for (int mt = 0; mt < 2; ++mt)
#pragma unroll
        for (int nt = 0; nt < 2; ++nt) {
            ushort4 h;
            h.x = f2bf(acc[mt][nt][0]); h.y = f2bf(acc[mt][nt][1]);
            h.z = f2bf(acc[mt][nt][2]); h.w = f2bf(acc[mt][nt][3]);
            *(ushort4*)&Yl[lid * 264 + nt * 128 + 32 * w + mt * 16 + q * 4] = h;
        }
    __syncthreads();

    // F2: C[(p,m)][ky] = sum_k A2[(p,m)][k] Yl[ky][k];  M=64 N=16 K=256
    f32x4 acc2 = {};
    const unsigned short* A2g = tab + TAB_A2;
#pragma unroll
    for (int ks = 0; ks < 8; ++ks) {
        bf16x8 a = *(const bf16x8*)&A2g[(16 * w + lid) * 256 + ks * 32 + q * 8];
        bf16x8 b = *(const bf16x8*)&Yl[lid * 264 + ks * 32 + q * 8];
        acc2 = mfma16(a, b, acc2);
    }
    int p = w >> 1, mb = (w & 1) * 16;
    float* xfp = ws + (p ? OFF_XFI : OFF_XFR) + (size_t)bid * 512;
#pragma unroll
    for (int r = 0; r < 4; ++r)
        xfp[(mb + q * 4 + r) * 16 + lid] = acc2[r];
}

// ---------------- channel mix: yf[mode][b][o] = sum_i xf[bid][mode] * wt[mode][i][o] --
__global__ __launch_bounds__(256) void k_mix(float* ws) {
    __shared__ float2 xsh[1024];
    __shared__ float2 wsh[1024];
    int t = threadIdx.x;
    int mode = blockIdx.x;
    const float* xfr = ws + OFF_XFR;
    const float* xfi = ws + OFF_XFI;
#pragma unroll
    for (int r = 0; r < 4; ++r) {
        int idx = t + 256 * r;
        xsh[idx] = make_float2(xfr[(size_t)idx * 512 + mode], xfi[(size_t)idx * 512 + mode]);
    }
    const float4* wg = (const float4*)((const float2*)(ws + OFF_WT) + (size_t)mode * 1024);
    float4* ws4 = (float4*)wsh;
    ws4[t] = wg[t]; ws4[t + 256] = wg[t + 256];
    __syncthreads();
    int o = t & 31, b0 = t >> 5;
    float ar[4] = {0, 0, 0, 0}, ai[4] = {0, 0, 0, 0};
    for (int i = 0; i < 32; ++i) {
        float2 wv = wsh[i * 32 + o];
#pragma unroll
        for (int bb = 0; bb < 4; ++bb) {
            float2 xv = xsh[(b0 + 8 * bb) * 32 + i];
            ar[bb] = fmaf(xv.x, wv.x, fmaf(-xv.y, wv.y, ar[bb]));
            ai[bb] = fmaf(xv.x, wv.y, fmaf( xv.y, wv.x, ai[bb]));
        }
    }
    float2* yf = (float2*)(ws + OFF_YF) + (size_t)mode * 1024;
#pragma unroll
    for (int bb = 0; bb < 4; ++bb)
        yf[(b0 + 8 * bb) * 32 + o] = make_float2(ar[bb], ai[bb]);
}

// ---------------- inverse: yf[.][bid] --MFMA--> out[bid,:,:] --------------------------
__global__ __launch_bounds__(256) void k_i(const float* __restrict__ ws, float* __restrict__ out) {
    __shared__ __align__(16) unsigned short A3l[128 * 72];
    __shared__ __align__(16) unsigned short E4l[128 * 40];
    __shared__ __align__(16) unsigned short Zl[128 * 40];    // [x][k=p*16+ky]
    __shared__ __align__(16) unsigned short Bl[32 * 72];     // [(p,ky)][k=c*32+m]
    __shared__ float2 zm[512];
    int t = threadIdx.x, bid = blockIdx.x;
    const unsigned short* tab = (const unsigned short*)(ws + OFF_TAB);

    for (int c = t; c < 1024; c += 256) {     // A3: 128x64 -> stride 72
        int row = c >> 3, seg = c & 7;
        *(uint4*)&A3l[row * 72 + seg * 8] = *(const uint4*)&tab[TAB_A3 + row * 64 + seg * 8];
    }
    for (int c = t; c < 512; c += 256) {      // E4t: 128x32 -> stride 40
        int row = c >> 2, seg = c & 3;
        *(uint4*)&E4l[row * 40 + seg * 8] = *(const uint4*)&tab[TAB_E4 + row * 32 + seg * 8];
    }
    const float2* yf = (const float2*)(ws + OFF_YF);
    zm[t]       = yf[(size_t)t * 1024 + bid];
    zm[t + 256] = yf[(size_t)(t + 256) * 1024 + bid];
    __syncthreads();

    // build Bl from Yf (complex-as-real with sign trick)
    {
        int n = t >> 3, k0 = (t & 7) * 8;
        int p = n >> 4, ky = n & 15;
        ushort4 h0, h1;
        unsigned short hh[8];
#pragma unroll
        for (int j = 0; j < 8; ++j) {
            int k = k0 + j, c = k >> 5, m = k & 31;
            float2 v = zm[m * 16 + ky];
            float val = (p == 0) ? (c == 0 ? v.x : v.y) : (c == 0 ? v.y : -v.x);
            hh[j] = f2bf(val);
        }
        h0.x = hh[0]; h0.y = hh[1]; h0.z = hh[2]; h0.w = hh[3];
        h1.x = hh[4]; h1.y = hh[5]; h1.z = hh[6]; h1.w = hh[7];
        *(ushort4*)&Bl[n * 72 + k0]     = h0;
        *(ushort4*)&Bl[n * 72 + k0 + 4] = h1;
    }
    __syncthreads();

    int lid = t & 15, q = (t >> 4) & 3, w = t >> 6;

    // I1: Z[x][(p,ky)] = sum_k A3[x][k] Bl[(p,ky)][k];  M=128 N=32 K=64
    f32x4 acc[2][2] = {};
#pragma unroll
    for (int ks = 0; ks < 2; ++ks) {
        bf16x8 a0 = *(const bf16x8*)&A3l[(32 * w + lid) * 72 + ks * 32 + q * 8];
        bf16x8 a1 = *(const bf16x8*)&A3l[(32 * w + 16 + lid) * 72 + ks * 32 + q * 8];
        bf16x8 b0 = *(const bf16x8*)&Bl[lid * 72 + ks * 32 + q * 8];
        bf16x8 b1 = *(const bf16x8*)&Bl[(16 + lid) * 72 + ks * 32 + q * 8];
        acc[0][0] = mfma16(a0, b0, acc[0][0]);
        acc[0][1] = mfma16(a0, b1, acc[0][1]);
        acc[1][0] = mfma16(a1, b0, acc[1][0]);
        acc[1][1] = mfma16(a1, b1, acc[1][1]);
    }
    // epilogue: Z -> Zl[x][p*16+ky] bf16
#pragma unroll
    for (int mt = 0; mt < 2; ++mt)
#pragma unroll
        for (int nt = 0; nt < 2; ++nt)
#pragma unroll
            for (int r = 0; r < 4; ++r)
                Zl[(32 * w + mt * 16 + q * 4 + r) * 40 + nt * 16 + lid] =
                    f2bf(acc[mt][nt][r]);
    __syncthreads();

    // I2: out[x][y] = sum_k Zl[x][k] E4t[y][k];  M=128 N=128 K=32
    f32x4 acc2[2][8];
#pragma unroll
    for (int mt = 0; mt < 2; ++mt) {
        bf16x8 a = *(const bf16x8*)&Zl[(32 * w + mt * 16 + lid) * 40 + q * 8];
#pragma unroll
        for (int nt = 0; nt < 8; ++nt) {
            bf16x8 b = *(const bf16x8*)&E4l[(nt * 16 + lid) * 40 + q * 8];
            f32x4 z = {};
            acc2[mt][nt] = mfma16(a, b, z);
        }
    }
    float* og = out + (size_t)bid * 16384;
#pragma unroll
    for (int mt = 0; mt < 2; ++mt)
#pragma unroll
        for (int r = 0; r < 4; ++r)
#pragma unroll
            for (int nt = 0; nt < 8; ++nt)
                og[(32 * w + mt * 16 + q * 4 + r) * 128 + nt * 16 + lid] = acc2[mt][nt][r];
}

extern "C" void kernel_launch(void* const* d_in, const int* in_sizes, int n_in,
                              void* d_out, int out_size, void* d_ws, size_t ws_size,
                              hipStream_t stream) {
    const float* x  = (const float*)d_in[0];
    const float* wr = (const float*)d_in[1];
    const float* wi = (const float*)d_in[2];
    float* out = (float*)d_out;
    float* ws  = (float*)d_ws;
    k_prep_e <<<dim3(128),  dim3(256), 0, stream>>>(ws);
    k_prep_wt<<<dim3(1024), dim3(256), 0, stream>>>(wr, wi, ws);
    k_f      <<<dim3(1024), dim3(256), 0, stream>>>(x, ws);
    k_mix    <<<dim3(512),  dim3(256), 0, stream>>>(ws);
    k_i      <<<dim3(1024), dim3(256), 0, stream>>>(ws, out);
}

// Round 5
// 144.358 us; speedup vs baseline: 1.5775x; 1.0065x over previous
//
#include <hip/hip_runtime.h>

#define PI_D 3.14159265358979323846

typedef __attribute__((ext_vector_type(8))) short bf16x8;
typedef __attribute__((ext_vector_type(4))) float f32x4;

static __device__ inline f32x4 mfma16(bf16x8 a, bf16x8 b, f32x4 c) {
    return __builtin_amdgcn_mfma_f32_16x16x32_bf16(a, b, c, 0, 0, 0);
}

static __device__ inline unsigned short f2bf(float f) {
    union { float f; unsigned u; } v; v.f = f;
    unsigned u = v.u;
    u += 0x7fffu + ((u >> 16) & 1u);   // RNE
    return (unsigned short)(u >> 16);
}
static __device__ inline float bf2f(unsigned short h) {
    union { unsigned u; float f; } v; v.u = ((unsigned)h) << 16;
    return v.f;
}

// ---- ws float layout ----------------------------------------------------------------
#define OFF_TAB 0                         // 32768 bf16 = 16384 floats
#define OFF_WT3  16384                    // wt3[o][i][mode] cplx: 1024*512 float2 = 1,048,576 fl
#define OFF_XFR  (16384 + 1048576)        // 1024 bids x 512 modes f32 (re)
#define OFF_XFI  (OFF_XFR + 524288)       // (im)
// total = 2,113,536 floats ~ 8.45 MB

// table offsets in u16 units within OFF_TAB
#define TAB_E1 0        // [32 n=c*16+ky][128 w]
#define TAB_A2 4096     // [64 row=p*32+m][256 k=c*128+x]
#define TAB_A3 20480    // [128 x][64 k=c*32+m]
#define TAB_E4 28672    // [128 y][32 k=p*16+ky]

// ---------------- table prep (bf16) ---------------------------------------------------
__global__ __launch_bounds__(256) void k_prep_e(float* ws) {
    int gid = blockIdx.x * 256 + threadIdx.x;   // 0..32767
    unsigned short* tab = (unsigned short*)(ws + OFF_TAB);
    const float W128 = (float)(2.0 * PI_D / 128.0);
    if (gid < 4096) {                       // E1t: forward y-DFT, x(1/128) scale
        int n = gid >> 7, w = gid & 127;
        int ky = n & 15, c = n >> 4;
        float th = ((w * ky) & 127) * W128;
        float val = (c ? -sinf(th) : cosf(th)) * (1.f / 128.f);
        tab[TAB_E1 + gid] = f2bf(val);
    } else if (gid < 20480) {               // A2: forward x-DFT (complex-as-real)
        int idx = gid - 4096;
        int row = idx >> 8, k = idx & 255;
        int p = row >> 5, m = row & 31;
        int c = k >> 7, xx = k & 127;
        int kx = (m < 16) ? m : 96 + m;
        float th = ((xx * kx) & 127) * W128;
        float er = cosf(th), ei = -sinf(th);
        float val = (p == 0) ? (c == 0 ? er : -ei) : (c == 0 ? ei : er);
        tab[TAB_A2 + idx] = f2bf(val);
    } else if (gid < 28672) {               // A3: inverse x-DFT
        int idx = gid - 20480;
        int xx = idx >> 6, k = idx & 63;
        int c = k >> 5, m = k & 31;
        int kx = (m < 16) ? m : 96 + m;
        float th = ((xx * kx) & 127) * W128;
        float er = cosf(th), ei = sinf(th);
        float val = (c == 0) ? er : -ei;
        tab[TAB_A3 + idx] = f2bf(val);
    } else {                                // E4t: inverse y-DFT w/ hermitian weights
        int idx = gid - 28672;
        int y = idx >> 5, k = idx & 31;
        int p = k >> 4, ky = k & 15;
        float th = ((y * ky) & 127) * W128;
        float sc = (ky == 0 ? 1.f : 2.f) / 128.f;
        float val = (p == 0) ? sc * cosf(th) : -sc * sinf(th);
        tab[TAB_E4 + idx] = f2bf(val);
    }
}

// ---------------- weight relayout: w[i][o][m][ky] -> wt3[(o*32+i)][mode] (cplx f32) ----
__global__ __launch_bounds__(256) void k_prep_wt2(const float* __restrict__ wr,
                                                  const float* __restrict__ wi,
                                                  float* ws) {
    int bid = blockIdx.x;            // o*32 + i
    int o = bid >> 5, i = bid & 31;
    int t = threadIdx.x;
    const float* r  = wr + (size_t)(i * 32 + o) * 512;
    const float* im = wi + (size_t)(i * 32 + o) * 512;
    float2* dst = (float2*)(ws + OFF_WT3) + (size_t)bid * 512;
    dst[t]       = make_float2(r[t],       im[t]);
    dst[t + 256] = make_float2(r[t + 256], im[t + 256]);
}

// ---------------- forward: x[bid,:,:] --MFMA--> xfr/xfi[bid][mode] --------------------
__global__ __launch_bounds__(256) void k_f(const float* __restrict__ x, float* ws) {
    __shared__ __align__(16) unsigned short Xl[128 * 136];   // x image bf16, pad->16B rows
    __shared__ __align__(16) unsigned short E1l[32 * 136];   // E1t staged
    __shared__ __align__(16) unsigned short Yl[16 * 264];    // Y: [ky][k=c*128+x]
    int t = threadIdx.x, bid = blockIdx.x;
    const unsigned short* tab = (const unsigned short*)(ws + OFF_TAB);

    // stage E1t (32x128 -> stride 136)
    for (int c = t; c < 512; c += 256) {
        int row = c >> 4, seg = c & 15;
        *(uint4*)&E1l[row * 136 + seg * 8] = *(const uint4*)&tab[TAB_E1 + row * 128 + seg * 8];
    }
    // stage X (f32 -> bf16)
    const float* xim = x + (size_t)bid * 16384;
    for (int it = 0; it < 16; ++it) {
        int row = it * 8 + (t >> 5), c4 = (t & 31) * 4;
        float4 v = *(const float4*)(xim + row * 128 + c4);
        ushort4 h;
        h.x = f2bf(v.x); h.y = f2bf(v.y); h.z = f2bf(v.z); h.w = f2bf(v.w);
        *(ushort4*)&Xl[row * 136 + c4] = h;
    }
    __syncthreads();

    int lid = t & 15, q = (t >> 4) & 3, w = t >> 6;

    // F1: C[x][(c,ky)] = sum_w X[x][w] E1t[(c,ky)][w];  M=128 N=32 K=128
    f32x4 acc[2][2] = {};
#pragma unroll
    for (int ks = 0; ks < 4; ++ks) {
        bf16x8 a0 = *(const bf16x8*)&Xl[(32 * w + lid) * 136 + ks * 32 + q * 8];
        bf16x8 a1 = *(const bf16x8*)&Xl[(32 * w + 16 + lid) * 136 + ks * 32 + q * 8];
        bf16x8 b0 = *(const bf16x8*)&E1l[lid * 136 + ks * 32 + q * 8];
        bf16x8 b1 = *(const bf16x8*)&E1l[(16 + lid) * 136 + ks * 32 + q * 8];
        acc[0][0] = mfma16(a0, b0, acc[0][0]);
        acc[0][1] = mfma16(a0, b1, acc[0][1]);
        acc[1][0] = mfma16(a1, b0, acc[1][0]);
        acc[1][1] = mfma16(a1, b1, acc[1][1]);
    }
    // epilogue: Y -> Yl[ky][c*128+x] bf16
#pragma unroll
    for (int mt = 0; mt < 2; ++mt)
#pragma unroll
        for (int nt = 0; nt < 2; ++nt) {
            ushort4 h;
            h.x = f2bf(acc[mt][nt][0]); h.y = f2bf(acc[mt][nt][1]);
            h.z = f2bf(acc[mt][nt][2]); h.w = f2bf(acc[mt][nt][3]);
            *(ushort4*)&Yl[lid * 264 + nt * 128 + 32 * w + mt * 16 + q * 4] = h;
        }
    __syncthreads();

    // F2: C[(p,m)][ky] = sum_k A2[(p,m)][k] Yl[ky][k];  M=64 N=16 K=256
    f32x4 acc2 = {};
    const unsigned short* A2g = tab + TAB_A2;
#pragma unroll
    for (int ks = 0; ks < 8; ++ks) {
        bf16x8 a = *(const bf16x8*)&A2g[(16 * w + lid) * 256 + ks * 32 + q * 8];
        bf16x8 b = *(const bf16x8*)&Yl[lid * 264 + ks * 32 + q * 8];
        acc2 = mfma16(a, b, acc2);
    }
    int p = w >> 1, mb = (w & 1) * 16;
    float* xfp = ws + (p ? OFF_XFI : OFF_XFR) + (size_t)bid * 512;
#pragma unroll
    for (int r = 0; r < 4; ++r)
        xfp[(mb + q * 4 + r) * 16 + lid] = acc2[r];
}

// ---------------- fused mix + inverse: block (b,o) -> out[b,o,:,:] --------------------
// Split-bf16 (hi+lo) for Bl and Zl: removes the two dominant quantization error terms.
__global__ __launch_bounds__(256) void k_im(const float* __restrict__ ws, float* __restrict__ out) {
    __shared__ __align__(16) unsigned short A3l[128 * 72];
    __shared__ __align__(16) unsigned short E4l[128 * 40];
    __shared__ __align__(16) unsigned short Zlh[128 * 40];   // [x][k=p*16+ky] hi
    __shared__ __align__(16) unsigned short Zll[128 * 40];   // lo residual
    __shared__ __align__(16) unsigned short Blh[32 * 72];    // [(p,ky)][k=c*32+m] hi
    __shared__ __align__(16) unsigned short Bll[32 * 72];    // lo residual
    __shared__ float2 zm[512];
    int t = threadIdx.x, bid = blockIdx.x;                   // b*32 + o
    int b = bid >> 5, o = bid & 31;
    const unsigned short* tab = (const unsigned short*)(ws + OFF_TAB);

    for (int c = t; c < 1024; c += 256) {     // A3: 128x64 -> stride 72
        int row = c >> 3, seg = c & 7;
        *(uint4*)&A3l[row * 72 + seg * 8] = *(const uint4*)&tab[TAB_A3 + row * 64 + seg * 8];
    }
    for (int c = t; c < 512; c += 256) {      // E4t: 128x32 -> stride 40
        int row = c >> 2, seg = c & 3;
        *(uint4*)&E4l[row * 40 + seg * 8] = *(const uint4*)&tab[TAB_E4 + row * 32 + seg * 8];
    }

    // ---- channel mix, f32: zm[mode] = sum_i xf[b,i,mode] * w3[o,i,mode]
    {
        const float* xfr = ws + OFF_XFR;
        const float* xfi = ws + OFF_XFI;
        const float* w3  = ws + OFF_WT3;     // float2[(o*32+i)*512 + mode]
        float a0r = 0.f, a0i = 0.f, a1r = 0.f, a1i = 0.f;
#pragma unroll 4
        for (int i = 0; i < 32; ++i) {
            const float2 xr2 = *(const float2*)(xfr + (size_t)(b * 32 + i) * 512 + 2 * t);
            const float2 xi2 = *(const float2*)(xfi + (size_t)(b * 32 + i) * 512 + 2 * t);
            const float4 w4  = *(const float4*)(w3 + ((size_t)(o * 32 + i) * 512 + 2 * t) * 2);
            a0r = fmaf(xr2.x, w4.x, fmaf(-xi2.x, w4.y, a0r));
            a0i = fmaf(xr2.x, w4.y, fmaf( xi2.x, w4.x, a0i));
            a1r = fmaf(xr2.y, w4.z, fmaf(-xi2.y, w4.w, a1r));
            a1i = fmaf(xr2.y, w4.w, fmaf( xi2.y, w4.z, a1i));
        }
        zm[2 * t]     = make_float2(a0r, a0i);
        zm[2 * t + 1] = make_float2(a1r, a1i);
    }
    __syncthreads();

    // build Blh/Bll from zm (complex-as-real with sign trick; hi + residual-lo)
    {
        int n = t >> 3, k0 = (t & 7) * 8;
        int p = n >> 4, ky = n & 15;
        unsigned short hh[8], hl[8];
#pragma unroll
        for (int j = 0; j < 8; ++j) {
            int k = k0 + j, c = k >> 5, m = k & 31;
            float2 v = zm[m * 16 + ky];
            float val = (p == 0) ? (c == 0 ? v.x : v.y) : (c == 0 ? v.y : -v.x);
            unsigned short vh = f2bf(val);
            hh[j] = vh;
            hl[j] = f2bf(val - bf2f(vh));
        }
        ushort4 a, bb;
        a.x = hh[0]; a.y = hh[1]; a.z = hh[2]; a.w = hh[3];
        bb.x = hh[4]; bb.y = hh[5]; bb.z = hh[6]; bb.w = hh[7];
        *(ushort4*)&Blh[n * 72 + k0]     = a;
        *(ushort4*)&Blh[n * 72 + k0 + 4] = bb;
        a.x = hl[0]; a.y = hl[1]; a.z = hl[2]; a.w = hl[3];
        bb.x = hl[4]; bb.y = hl[5]; bb.z = hl[6]; bb.w = hl[7];
        *(ushort4*)&Bll[n * 72 + k0]     = a;
        *(ushort4*)&Bll[n * 72 + k0 + 4] = bb;
    }
    __syncthreads();

    int lid = t & 15, q = (t >> 4) & 3, w = t >> 6;

    // I1: Z[x][(p,ky)] = sum_k A3[x][k] (Bh+Bl)[(p,ky)][k];  M=128 N=32 K=64, double-pumped
    f32x4 acc[2][2] = {};
#pragma unroll
    for (int ks = 0; ks < 2; ++ks) {
        bf16x8 a0  = *(const bf16x8*)&A3l[(32 * w + lid) * 72 + ks * 32 + q * 8];
        bf16x8 a1  = *(const bf16x8*)&A3l[(32 * w + 16 + lid) * 72 + ks * 32 + q * 8];
        bf16x8 bh0 = *(const bf16x8*)&Blh[lid * 72 + ks * 32 + q * 8];
        bf16x8 bh1 = *(const bf16x8*)&Blh[(16 + lid) * 72 + ks * 32 + q * 8];
        bf16x8 bl0 = *(const bf16x8*)&Bll[lid * 72 + ks * 32 + q * 8];
        bf16x8 bl1 = *(const bf16x8*)&Bll[(16 + lid) * 72 + ks * 32 + q * 8];
        acc[0][0] = mfma16(a0, bl0, acc[0][0]);
        acc[0][0] = mfma16(a0, bh0, acc[0][0]);
        acc[0][1] = mfma16(a0, bl1, acc[0][1]);
        acc[0][1] = mfma16(a0, bh1, acc[0][1]);
        acc[1][0] = mfma16(a1, bl0, acc[1][0]);
        acc[1][0] = mfma16(a1, bh0, acc[1][0]);
        acc[1][1] = mfma16(a1, bl1, acc[1][1]);
        acc[1][1] = mfma16(a1, bh1, acc[1][1]);
    }
    // epilogue: Z -> Zlh/Zll[x][p*16+ky] (hi + residual-lo)
#pragma unroll
    for (int mt = 0; mt < 2; ++mt)
#pragma unroll
        for (int nt = 0; nt < 2; ++nt)
#pragma unroll
            for (int r = 0; r < 4; ++r) {
                float z = acc[mt][nt][r];
                unsigned short zh = f2bf(z);
                int idx = (32 * w + mt * 16 + q * 4 + r) * 40 + nt * 16 + lid;
                Zlh[idx] = zh;
                Zll[idx] = f2bf(z - bf2f(zh));
            }
    __syncthreads();

    // I2: out[x][y] = sum_k (Zh+Zl)[x][k] E4t[y][k];  M=128 N=128 K=32, double-pumped
    f32x4 acc2[2][8];
#pragma unroll
    for (int mt = 0; mt < 2; ++mt) {
        bf16x8 ah = *(const bf16x8*)&Zlh[(32 * w + mt * 16 + lid) * 40 + q * 8];
        bf16x8 al = *(const bf16x8*)&Zll[(32 * w + mt * 16 + lid) * 40 + q * 8];
#pragma unroll
        for (int nt = 0; nt < 8; ++nt) {
            bf16x8 bb = *(const bf16x8*)&E4l[(nt * 16 + lid) * 40 + q * 8];
            f32x4 z = {};
            z = mfma16(al, bb, z);
            acc2[mt][nt] = mfma16(ah, bb, z);
        }
    }
    float* og = out + (size_t)bid * 16384;
#pragma unroll
    for (int mt = 0; mt < 2; ++mt)
#pragma unroll
        for (int r = 0; r < 4; ++r)
#pragma unroll
            for (int nt = 0; nt < 8; ++nt)
                og[(32 * w + mt * 16 + q * 4 + r) * 128 + nt * 16 + lid] = acc2[mt][nt][r];
}

extern "C" void kernel_launch(void* const* d_in, const int* in_sizes, int n_in,
                              void* d_out, int out_size, void* d_ws, size_t ws_size,
                              hipStream_t stream) {
    const float* x  = (const float*)d_in[0];
    const float* wr = (const float*)d_in[1];
    const float* wi = (const float*)d_in[2];
    float* out = (float*)d_out;
    float* ws  = (float*)d_ws;
    k_prep_e  <<<dim3(128),  dim3(256), 0, stream>>>(ws);
    k_prep_wt2<<<dim3(1024), dim3(256), 0, stream>>>(wr, wi, ws);
    k_f       <<<dim3(1024), dim3(256), 0, stream>>>(x, ws);
    k_im      <<<dim3(1024), dim3(256), 0, stream>>>(ws, out);
}